// Round 11
// baseline (69.814 us; speedup 1.0000x reference)
//
#include <hip/hip_runtime.h>

#define TWO_LOG2E 2.8853900817779268f

__device__ __forceinline__ float frcp(float x) {
#if __has_builtin(__builtin_amdgcn_rcpf)
  return __builtin_amdgcn_rcpf(x);
#else
  return 1.0f / x;
#endif
}
__device__ __forceinline__ float fexp2(float x) {
#if __has_builtin(__builtin_amdgcn_exp2f)
  return __builtin_amdgcn_exp2f(x);
#else
  return exp2f(x);
#endif
}
__device__ __forceinline__ unsigned short f2bf(float f) {  // RNE f32->bf16
  unsigned int u = __float_as_uint(f);
  u += 0x7fffu + ((u >> 16) & 1u);
  return (unsigned short)(u >> 16);
}
__device__ __forceinline__ unsigned int pack2bf(float lo, float hi) {
  return (unsigned int)f2bf(lo) | ((unsigned int)f2bf(hi) << 16);
}

using short8 = __attribute__((ext_vector_type(8))) short;
using f32x4v = __attribute__((ext_vector_type(4))) float;
using f32x16s = __attribute__((ext_vector_type(16))) float;
using f32x2 = __attribute__((ext_vector_type(2))) float;

__device__ __forceinline__ f32x2 pkfma(f32x2 a, f32x2 b, f32x2 c) {
  return __builtin_elementwise_fma(a, b, c);
}
__device__ __forceinline__ f32x2 splat2(float x) {
  f32x2 r;
  r.x = x;
  r.y = x;
  return r;
}
__device__ __forceinline__ f32x2 unpack_bf2(unsigned u) {  // (k-even, k-odd)
  f32x2 r;
  r.x = __uint_as_float(u << 16);
  r.y = __uint_as_float(u & 0xffff0000u);
  return r;
}
// s += sum_{i=0..3} v_i/(a_i*b_i+1) for BOTH k-parities, ONE rcp per parity.
__device__ __forceinline__ void cell4k(float a0, float a1, float a2, float a3,
                                       f32x2 b0, f32x2 b1, f32x2 b2, f32x2 b3,
                                       float v0, float v1, float v2, float v3,
                                       f32x2& s) {
  const f32x2 one = {1.f, 1.f};
  f32x2 x0 = pkfma(splat2(a0), b0, one);
  f32x2 x1 = pkfma(splat2(a1), b1, one);
  f32x2 x2 = pkfma(splat2(a2), b2, one);
  f32x2 x3 = pkfma(splat2(a3), b3, one);
  f32x2 p01 = x0 * x1, p23 = x2 * x3;
  f32x2 n01 = pkfma(splat2(v0), x1, splat2(v1) * x0);
  f32x2 n23 = pkfma(splat2(v2), x3, splat2(v3) * x2);
  f32x2 num = pkfma(n01, p23, n23 * p01);
  f32x2 den = p01 * p23;
  f32x2 r;
  r.x = frcp(den.x);
  r.y = frcp(den.y);
  s = pkfma(num, r, s);
}

// ---------------------------------------------------------------------------
// k_pre: fused projections + value transpose.
//  y==0: Aexp[m][128] = exp(2*query@w1^T) (f32) | BexpT[h][4096] =
//        exp(2*key@w2^T) transposed (bf16, via swapped-operand MFMA).
//        BM=16, BN=128, BK=64, T14 register prefetch. x: 2 proj x 256 m-blocks.
//  y==1: valT[b][n][k] = bf16(value[b][k][n]), 64x64 tiles, x = b*64+kt*8+nt.
// grid (512, 2), block 256.
// ---------------------------------------------------------------------------
__global__ __launch_bounds__(256) void k_pre(
    const float* __restrict__ query, const float* __restrict__ key,
    const float* __restrict__ w1, const float* __restrict__ w2,
    const float* __restrict__ value,
    float* __restrict__ Aout, unsigned short* __restrict__ BoutT,
    unsigned short* __restrict__ valT) {
  __shared__ __align__(16) char Abuf[16 * 128];   // [m][k] bf16, swizzled
  __shared__ __align__(16) char Bbuf[128 * 128];  // [n][k] bf16, swizzled
  __shared__ unsigned short ts[64][66];           // valT transpose buffer

  const int t = threadIdx.x;

  if (blockIdx.y == 0) {  // ---- projections ----
    const int px = blockIdx.x;
    const bool isB = px >= 256;
    const float* in = isB ? key : query;
    const float* wm = isB ? w2 : w1;
    const int m0g = (px & 255) * 16;
    const int w = t >> 6, l = t & 63;

    f32x4v acc[2];
    acc[0] = 0;
    acc[1] = 0;

    float4 aS;
    float4 wS[4][2];

#define P_LOAD(k0_)                                                        \
  {                                                                        \
    aS = *(const float4*)&in[(m0g + (t >> 4)) * 512 + (k0_) + (t & 15) * 4]; \
    _Pragma("unroll") for (int i = 0; i < 4; ++i) {                        \
      int tt = t + i * 256;                                                \
      int row = tt >> 3, g = tt & 7;                                       \
      const float* src = &wm[row * 512 + (k0_) + g * 8];                   \
      wS[i][0] = *(const float4*)src;                                      \
      wS[i][1] = *(const float4*)(src + 4);                                \
    }                                                                      \
  }
#define P_WRITE()                                                          \
  {                                                                        \
    int arow = t >> 4, q4 = t & 15;                                        \
    *(uint2*)(Abuf + arow * 128 + (((q4 >> 1) ^ (arow & 7)) << 4) +        \
              ((q4 & 1) << 3)) =                                           \
        make_uint2(pack2bf(aS.x, aS.y), pack2bf(aS.z, aS.w));              \
    _Pragma("unroll") for (int i = 0; i < 4; ++i) {                        \
      int tt = t + i * 256;                                                \
      int row = tt >> 3, g = tt & 7;                                       \
      uint4 p = make_uint4(                                                \
          pack2bf(wS[i][0].x, wS[i][0].y), pack2bf(wS[i][0].z, wS[i][0].w),\
          pack2bf(wS[i][1].x, wS[i][1].y), pack2bf(wS[i][1].z, wS[i][1].w));\
      *(uint4*)(Bbuf + row * 128 + ((g ^ (row & 7)) << 4)) = p;            \
    }                                                                      \
  }

    P_LOAD(0);
#pragma unroll
    for (int ks8 = 0; ks8 < 8; ++ks8) {
      if (ks8) __syncthreads();  // prior reads done before overwrite
      P_WRITE();
      if (ks8 < 7) P_LOAD(ks8 * 64 + 64);  // in flight under compute
      __syncthreads();
#pragma unroll
      for (int ks = 0; ks < 2; ++ks) {
        const int gb = ks * 4 + (l >> 4);
        const int ra = l & 15;
        short8 af = *(const short8*)(Abuf + ra * 128 + ((gb ^ (ra & 7)) << 4));
#pragma unroll
        for (int ni = 0; ni < 2; ++ni) {
          const int rb = w * 32 + ni * 16 + (l & 15);
          short8 bf_ = *(const short8*)(Bbuf + rb * 128 + ((gb ^ (rb & 7)) << 4));
          if (isB)  // transposed tile: rows=h, cols=m
            acc[ni] = __builtin_amdgcn_mfma_f32_16x16x32_bf16(bf_, af, acc[ni], 0, 0, 0);
          else
            acc[ni] = __builtin_amdgcn_mfma_f32_16x16x32_bf16(af, bf_, acc[ni], 0, 0, 0);
        }
      }
    }
#undef P_LOAD
#undef P_WRITE
    if (!isB) {
#pragma unroll
      for (int ni = 0; ni < 2; ++ni) {
        int col = w * 32 + ni * 16 + (l & 15);  // h
#pragma unroll
        for (int j = 0; j < 4; ++j) {
          int row = m0g + (l >> 4) * 4 + j;  // m
          Aout[row * 128 + col] = fexp2(acc[ni][j] * TWO_LOG2E);
        }
      }
    } else {
      int m = m0g + (l & 15);  // contiguous across lanes
#pragma unroll
      for (int ni = 0; ni < 2; ++ni)
#pragma unroll
        for (int j = 0; j < 4; ++j) {
          int h = w * 32 + ni * 16 + (l >> 4) * 4 + j;
          BoutT[h * 4096 + m] = f2bf(fexp2(acc[ni][j] * TWO_LOG2E));
        }
    }
  } else {  // ---- valT ----
    const int x = blockIdx.x;
    const int b = x >> 6, k0 = ((x >> 3) & 7) * 64, n0 = (x & 7) * 64;
    {
      int kr = t >> 4, n4 = (t & 15) * 4;
#pragma unroll
      for (int i = 0; i < 4; ++i) {
        float4 f =
            *(const float4*)&value[((b * 512) + k0 + kr + 16 * i) * 512 + n0 + n4];
        *(ushort4*)&ts[kr + 16 * i][n4] =
            make_ushort4(f2bf(f.x), f2bf(f.y), f2bf(f.z), f2bf(f.w));
      }
    }
    __syncthreads();
    {
      int nw = t >> 4, k4 = (t & 15) * 4;
#pragma unroll
      for (int i = 0; i < 4; ++i) {
        int n = nw + 16 * i;
        ushort4 o = make_ushort4(ts[k4 + 0][n], ts[k4 + 1][n], ts[k4 + 2][n],
                                 ts[k4 + 3][n]);
        *(ushort4*)&valT[((b * 512) + n0 + n) * 512 + k0 + k4] = o;
      }
    }
  }
}

// ---------------------------------------------------------------------------
// K2: S[q,k] = sum_h v[h]/(A[q,h]*B[k,h]+1);  attn = softmax_k(-2S).
// No LDS/barriers in hot loop. B from BexpT[h][k]: lane owns k-pair (2l,2l+1);
// 16 dwords per 16-h chunk, DOUBLE-BUFFERED in regs (prefetch one hc ahead).
// k-parity in packed-f32 (v_pk_fma_f32) halves. A,v SGPR-broadcast
// (s_load_dwordx16, issue-early / wait-late). 2 q-rows/block.
// grid (256,8) = 8 blocks/CU.
// ---------------------------------------------------------------------------
__global__ __launch_bounds__(256, 8) void k_score_softmax(
    const float* __restrict__ Aexp, const unsigned short* __restrict__ BexpT,
    const float* __restrict__ vw, float* __restrict__ attn) {
  __shared__ float red[4][2];

  const int tid = threadIdx.x;
  const int b = blockIdx.y;
  const int qbase = blockIdx.x * 2;
  const int wav = tid >> 6;   // k-quarter
  const int lane = tid & 63;

  const unsigned* const bbase32 = (const unsigned*)(BexpT + b * 512);
  const int kidx = wav * 64 + lane;  // dword index within a k-row

  const float* const pa0 =
      Aexp + __builtin_amdgcn_readfirstlane((b * 512 + qbase) * 128);
  const float* const pa1 = pa0 + 128;
  const float* const pv = vw;

  f32x2 accq0 = {0.f, 0.f};  // q0: (k-even, k-odd)
  f32x2 accq1 = {0.f, 0.f};  // q1

  unsigned ua[16], ub[16];
#define K2_LOADB(dst_, hc_)                                                \
  {                                                                        \
    _Pragma("unroll") for (int j = 0; j < 16; ++j)                         \
        dst_[j] = bbase32[(hc_) * 32768 + j * 2048 + kidx];                \
  }
#define K2_STEP(hc_, CUR_, NXT_, LAST_)                                    \
  {                                                                        \
    f32x16s sa0, sa1, sv;                                                  \
    unsigned soff = (unsigned)((hc_) * 64);                                \
    asm volatile(                                                          \
        "s_load_dwordx16 %0, %3, %6\n\t"                                   \
        "s_load_dwordx16 %1, %4, %6\n\t"                                   \
        "s_load_dwordx16 %2, %5, %6"                                       \
        : "=&s"(sa0), "=&s"(sa1), "=&s"(sv)                                \
        : "s"(pa0), "s"(pa1), "s"(pv), "s"(soff));                         \
    if (!(LAST_)) K2_LOADB(NXT_, (hc_) + 1);                               \
    asm volatile("s_waitcnt lgkmcnt(0)" : "+s"(sa0), "+s"(sa1), "+s"(sv)); \
    _Pragma("unroll") for (int g = 0; g < 4; ++g) {                        \
      f32x2 b0 = unpack_bf2(CUR_[g * 4 + 0]);                              \
      f32x2 b1 = unpack_bf2(CUR_[g * 4 + 1]);                              \
      f32x2 b2 = unpack_bf2(CUR_[g * 4 + 2]);                              \
      f32x2 b3 = unpack_bf2(CUR_[g * 4 + 3]);                              \
      const int h = g * 4;                                                 \
      cell4k(sa0[h], sa0[h + 1], sa0[h + 2], sa0[h + 3], b0, b1, b2, b3,   \
             sv[h], sv[h + 1], sv[h + 2], sv[h + 3], accq0);               \
      cell4k(sa1[h], sa1[h + 1], sa1[h + 2], sa1[h + 3], b0, b1, b2, b3,   \
             sv[h], sv[h + 1], sv[h + 2], sv[h + 3], accq1);               \
    }                                                                      \
  }

  K2_LOADB(ua, 0);
  K2_STEP(0, ua, ub, false)
  K2_STEP(1, ub, ua, false)
  K2_STEP(2, ua, ub, false)
  K2_STEP(3, ub, ua, false)
  K2_STEP(4, ua, ub, false)
  K2_STEP(5, ub, ua, false)
  K2_STEP(6, ua, ub, false)
  K2_STEP(7, ub, ua, true)
#undef K2_LOADB
#undef K2_STEP

  float S00 = accq0.x, S01 = accq0.y, S10 = accq1.x, S11 = accq1.y;

  // softmax over k of (-2S): max(score) <-> min(S). k spans lanes+waves.
  float mn0 = fminf(S00, S01);
  float mn1 = fminf(S10, S11);
#pragma unroll
  for (int off = 32; off > 0; off >>= 1) {
    mn0 = fminf(mn0, __shfl_xor(mn0, off));
    mn1 = fminf(mn1, __shfl_xor(mn1, off));
  }
  if (lane == 0) { red[wav][0] = mn0; red[wav][1] = mn1; }
  __syncthreads();
  mn0 = fminf(fminf(red[0][0], red[1][0]), fminf(red[2][0], red[3][0]));
  mn1 = fminf(fminf(red[0][1], red[1][1]), fminf(red[2][1], red[3][1]));
  __syncthreads();  // before red reuse

  float P00 = fexp2((mn0 - S00) * TWO_LOG2E);
  float P01 = fexp2((mn0 - S01) * TWO_LOG2E);
  float P10 = fexp2((mn1 - S10) * TWO_LOG2E);
  float P11 = fexp2((mn1 - S11) * TWO_LOG2E);
  float sum0 = P00 + P01, sum1 = P10 + P11;
#pragma unroll
  for (int off = 32; off > 0; off >>= 1) {
    sum0 += __shfl_xor(sum0, off);
    sum1 += __shfl_xor(sum1, off);
  }
  if (lane == 0) { red[wav][0] = sum0; red[wav][1] = sum1; }
  __syncthreads();
  float r0 = frcp(red[0][0] + red[1][0] + red[2][0] + red[3][0]);
  float r1 = frcp(red[0][1] + red[1][1] + red[2][1] + red[3][1]);

  const int row0 = (b * 512 + qbase) * 512;
  const int k0 = wav * 128 + lane * 2;
  *(float2*)&attn[row0 + k0] = make_float2(P00 * r0, P01 * r0);
  *(float2*)&attn[row0 + 512 + k0] = make_float2(P10 * r1, P11 * r1);
}

// ---------------------------------------------------------------------------
// K3: context[b] = attn[b] @ value[b] via bf16 MFMA 16x16x32.
// Tile 64x64, BK=64, 4 waves (2x2), wave tile 32x32 (2x2 frags).
// grid (8,8,8), block 256.
// ---------------------------------------------------------------------------
__global__ __launch_bounds__(256) void k_context_mfma(
    const float* __restrict__ attn, const unsigned short* __restrict__ valT,
    float* __restrict__ ctx) {
  __shared__ __align__(16) char At[64 * 128];  // [m][k] bf16 swizzled, 8KB
  __shared__ __align__(16) char Bt[64 * 128];  // [n][k] bf16 swizzled, 8KB

  const int t = threadIdx.x;
  const int b = blockIdx.z;
  const int m0 = blockIdx.y * 64, n0 = blockIdx.x * 64;
  const int w = t >> 6, l = t & 63;
  const int wr = w >> 1, wc = w & 1;

  f32x4v acc[2][2];
  acc[0][0] = 0; acc[0][1] = 0; acc[1][0] = 0; acc[1][1] = 0;

  const int sr = t >> 2;
  const int sg = (t & 3);
  const int sswz = sr & 7;

  for (int k0 = 0; k0 < 512; k0 += 64) {
    if (k0) __syncthreads();
    {  // stage A: 16 f32 -> 16 bf16 per thread
      const float* src = &attn[(b * 512 + m0 + sr) * 512 + k0 + sg * 16];
      char* dst = At + sr * 128;
#pragma unroll
      for (int h = 0; h < 2; ++h) {
        float4 f0 = *(const float4*)(src + h * 8);
        float4 f1 = *(const float4*)(src + h * 8 + 4);
        uint4 p = make_uint4(pack2bf(f0.x, f0.y), pack2bf(f0.z, f0.w),
                             pack2bf(f1.x, f1.y), pack2bf(f1.z, f1.w));
        int g = sg * 2 + h;
        *(uint4*)(dst + ((g ^ sswz) << 4)) = p;
      }
      // stage B^T: 32 bf16 per thread (already bf16)
      const unsigned short* srcb = &valT[(b * 512 + n0 + sr) * 512 + k0];
      char* dstb = Bt + sr * 128;
#pragma unroll
      for (int h = 0; h < 2; ++h) {
        int g = sg + h * 4;
        uint4 vb = *(const uint4*)(srcb + g * 8);
        *(uint4*)(dstb + ((g ^ sswz) << 4)) = vb;
      }
    }
    __syncthreads();
#pragma unroll
    for (int ks = 0; ks < 2; ++ks) {
      const int gb = ks * 4 + (l >> 4);
      short8 af[2], bf_[2];
#pragma unroll
      for (int mi = 0; mi < 2; ++mi) {
        int ra = wr * 32 + mi * 16 + (l & 15);
        af[mi] = *(const short8*)(At + ra * 128 + ((gb ^ (ra & 7)) << 4));
      }
#pragma unroll
      for (int ni = 0; ni < 2; ++ni) {
        int rb = wc * 32 + ni * 16 + (l & 15);
        bf_[ni] = *(const short8*)(Bt + rb * 128 + ((gb ^ (rb & 7)) << 4));
      }
#pragma unroll
      for (int mi = 0; mi < 2; ++mi)
#pragma unroll
        for (int ni = 0; ni < 2; ++ni)
          acc[mi][ni] = __builtin_amdgcn_mfma_f32_16x16x32_bf16(
              af[mi], bf_[ni], acc[mi][ni], 0, 0, 0);
    }
  }
  __syncthreads();
#pragma unroll
  for (int mi = 0; mi < 2; ++mi)
#pragma unroll
    for (int ni = 0; ni < 2; ++ni) {
      int col = n0 + wc * 32 + ni * 16 + (l & 15);
#pragma unroll
      for (int j = 0; j < 4; ++j) {
        int row = m0 + wr * 32 + mi * 16 + (l >> 4) * 4 + j;
        ctx[(b * 512 + row) * 512 + col] = acc[mi][ni][j];
      }
    }
}

extern "C" void kernel_launch(void* const* d_in, const int* in_sizes, int n_in,
                              void* d_out, int out_size, void* d_ws, size_t ws_size,
                              hipStream_t stream) {
  const float* query = (const float*)d_in[0];
  const float* key   = (const float*)d_in[1];
  const float* value = (const float*)d_in[2];
  const float* w1    = (const float*)d_in[3];
  const float* w2    = (const float*)d_in[4];
  const float* v     = (const float*)d_in[5];

  float* attn = (float*)d_out;
  float* ctx  = attn + 8 * 512 * 512;

  float* Aexp = (float*)d_ws;                                    // 4096*128 f32
  unsigned short* BexpT = (unsigned short*)(Aexp + 4096 * 128);  // 128*4096 bf16
  unsigned short* valT = BexpT + 128 * 4096;                     // 8*512*512 bf16

  k_pre<<<dim3(512, 2), 256, 0, stream>>>(query, key, w1, w2, value,
                                          Aexp, BexpT, valT);
  k_score_softmax<<<dim3(256, 8), 256, 0, stream>>>(Aexp, BexpT, v, attn);
  k_context_mfma<<<dim3(8, 8, 8), 256, 0, stream>>>(attn, valT, ctx);
}

// Round 12
// 61.559 us; speedup vs baseline: 1.1341x; 1.1341x over previous
//
#include <hip/hip_runtime.h>

#define TWO_LOG2E 2.8853900817779268f

__device__ __forceinline__ float frcp(float x) {
#if __has_builtin(__builtin_amdgcn_rcpf)
  return __builtin_amdgcn_rcpf(x);
#else
  return 1.0f / x;
#endif
}
__device__ __forceinline__ float fexp2(float x) {
#if __has_builtin(__builtin_amdgcn_exp2f)
  return __builtin_amdgcn_exp2f(x);
#else
  return exp2f(x);
#endif
}
__device__ __forceinline__ unsigned short f2bf(float f) {  // RNE f32->bf16
  unsigned int u = __float_as_uint(f);
  u += 0x7fffu + ((u >> 16) & 1u);
  return (unsigned short)(u >> 16);
}
__device__ __forceinline__ unsigned int pack2bf(float lo, float hi) {
  return (unsigned int)f2bf(lo) | ((unsigned int)f2bf(hi) << 16);
}

using short8 = __attribute__((ext_vector_type(8))) short;
using f32x4v = __attribute__((ext_vector_type(4))) float;
using f32x8s = __attribute__((ext_vector_type(8))) float;
using f32x2 = __attribute__((ext_vector_type(2))) float;

__device__ __forceinline__ f32x2 pkfma(f32x2 a, f32x2 b, f32x2 c) {
  return __builtin_elementwise_fma(a, b, c);
}
__device__ __forceinline__ f32x2 splat2(float x) {
  f32x2 r;
  r.x = x;
  r.y = x;
  return r;
}
__device__ __forceinline__ f32x2 unpack_bf2(unsigned u) {  // (k-even, k-odd)
  f32x2 r;
  r.x = __uint_as_float(u << 16);
  r.y = __uint_as_float(u & 0xffff0000u);
  return r;
}
// s += sum_{i=0..3} v_i/(a_i*b_i+1) for BOTH k-parities, ONE rcp per parity.
__device__ __forceinline__ void cell4k(float a0, float a1, float a2, float a3,
                                       f32x2 b0, f32x2 b1, f32x2 b2, f32x2 b3,
                                       float v0, float v1, float v2, float v3,
                                       f32x2& s) {
  const f32x2 one = {1.f, 1.f};
  f32x2 x0 = pkfma(splat2(a0), b0, one);
  f32x2 x1 = pkfma(splat2(a1), b1, one);
  f32x2 x2 = pkfma(splat2(a2), b2, one);
  f32x2 x3 = pkfma(splat2(a3), b3, one);
  f32x2 p01 = x0 * x1, p23 = x2 * x3;
  f32x2 n01 = pkfma(splat2(v0), x1, splat2(v1) * x0);
  f32x2 n23 = pkfma(splat2(v2), x3, splat2(v3) * x2);
  f32x2 num = pkfma(n01, p23, n23 * p01);
  f32x2 den = p01 * p23;
  f32x2 r;
  r.x = frcp(den.x);
  r.y = frcp(den.y);
  s = pkfma(num, r, s);
}

// ---------------------------------------------------------------------------
// k_pre: fused projections + value transpose.
//  y==0: Aexp[m][128] = exp(2*query@w1^T) (f32) | BexpT[h][4096] =
//        exp(2*key@w2^T) transposed (bf16, via swapped-operand MFMA).
//        BM=16, BN=128, BK=64, T14 register prefetch. x: 2 proj x 256 m-blocks.
//  y==1: valT[b][n][k] = bf16(value[b][k][n]), 64x64 tiles.
// grid (512, 2), block 256.
// ---------------------------------------------------------------------------
__global__ __launch_bounds__(256) void k_pre(
    const float* __restrict__ query, const float* __restrict__ key,
    const float* __restrict__ w1, const float* __restrict__ w2,
    const float* __restrict__ value,
    float* __restrict__ Aout, unsigned short* __restrict__ BoutT,
    unsigned short* __restrict__ valT) {
  __shared__ __align__(16) char Abuf[16 * 128];   // [m][k] bf16, swizzled
  __shared__ __align__(16) char Bbuf[128 * 128];  // [n][k] bf16, swizzled
  __shared__ unsigned short ts[64][66];           // valT transpose buffer

  const int t = threadIdx.x;

  if (blockIdx.y == 0) {  // ---- projections ----
    const int px = blockIdx.x;
    const bool isB = px >= 256;
    const float* in = isB ? key : query;
    const float* wm = isB ? w2 : w1;
    const int m0g = (px & 255) * 16;
    const int w = t >> 6, l = t & 63;

    f32x4v acc[2];
    acc[0] = 0;
    acc[1] = 0;

    float4 aS;
    float4 wS[4][2];

#define P_LOAD(k0_)                                                        \
  {                                                                        \
    aS = *(const float4*)&in[(m0g + (t >> 4)) * 512 + (k0_) + (t & 15) * 4]; \
    _Pragma("unroll") for (int i = 0; i < 4; ++i) {                        \
      int tt = t + i * 256;                                                \
      int row = tt >> 3, g = tt & 7;                                       \
      const float* src = &wm[row * 512 + (k0_) + g * 8];                   \
      wS[i][0] = *(const float4*)src;                                      \
      wS[i][1] = *(const float4*)(src + 4);                                \
    }                                                                      \
  }
#define P_WRITE()                                                          \
  {                                                                        \
    int arow = t >> 4, q4 = t & 15;                                        \
    *(uint2*)(Abuf + arow * 128 + (((q4 >> 1) ^ (arow & 7)) << 4) +        \
              ((q4 & 1) << 3)) =                                           \
        make_uint2(pack2bf(aS.x, aS.y), pack2bf(aS.z, aS.w));              \
    _Pragma("unroll") for (int i = 0; i < 4; ++i) {                        \
      int tt = t + i * 256;                                                \
      int row = tt >> 3, g = tt & 7;                                       \
      uint4 p = make_uint4(                                                \
          pack2bf(wS[i][0].x, wS[i][0].y), pack2bf(wS[i][0].z, wS[i][0].w),\
          pack2bf(wS[i][1].x, wS[i][1].y), pack2bf(wS[i][1].z, wS[i][1].w));\
      *(uint4*)(Bbuf + row * 128 + ((g ^ (row & 7)) << 4)) = p;            \
    }                                                                      \
  }

    P_LOAD(0);
#pragma unroll
    for (int ks8 = 0; ks8 < 8; ++ks8) {
      if (ks8) __syncthreads();  // prior reads done before overwrite
      P_WRITE();
      if (ks8 < 7) P_LOAD(ks8 * 64 + 64);  // in flight under compute
      __syncthreads();
#pragma unroll
      for (int ks = 0; ks < 2; ++ks) {
        const int gb = ks * 4 + (l >> 4);
        const int ra = l & 15;
        short8 af = *(const short8*)(Abuf + ra * 128 + ((gb ^ (ra & 7)) << 4));
#pragma unroll
        for (int ni = 0; ni < 2; ++ni) {
          const int rb = w * 32 + ni * 16 + (l & 15);
          short8 bf_ = *(const short8*)(Bbuf + rb * 128 + ((gb ^ (rb & 7)) << 4));
          if (isB)  // transposed tile: rows=h, cols=m
            acc[ni] = __builtin_amdgcn_mfma_f32_16x16x32_bf16(bf_, af, acc[ni], 0, 0, 0);
          else
            acc[ni] = __builtin_amdgcn_mfma_f32_16x16x32_bf16(af, bf_, acc[ni], 0, 0, 0);
        }
      }
    }
#undef P_LOAD
#undef P_WRITE
    if (!isB) {
#pragma unroll
      for (int ni = 0; ni < 2; ++ni) {
        int col = w * 32 + ni * 16 + (l & 15);  // h
#pragma unroll
        for (int j = 0; j < 4; ++j) {
          int row = m0g + (l >> 4) * 4 + j;  // m
          Aout[row * 128 + col] = fexp2(acc[ni][j] * TWO_LOG2E);
        }
      }
    } else {
      int m = m0g + (l & 15);  // contiguous across lanes
#pragma unroll
      for (int ni = 0; ni < 2; ++ni)
#pragma unroll
        for (int j = 0; j < 4; ++j) {
          int h = w * 32 + ni * 16 + (l >> 4) * 4 + j;
          BoutT[h * 4096 + m] = f2bf(fexp2(acc[ni][j] * TWO_LOG2E));
        }
    }
  } else {  // ---- valT ----
    const int x = blockIdx.x;
    const int b = x >> 6, k0 = ((x >> 3) & 7) * 64, n0 = (x & 7) * 64;
    {
      int kr = t >> 4, n4 = (t & 15) * 4;
#pragma unroll
      for (int i = 0; i < 4; ++i) {
        float4 f =
            *(const float4*)&value[((b * 512) + k0 + kr + 16 * i) * 512 + n0 + n4];
        *(ushort4*)&ts[kr + 16 * i][n4] =
            make_ushort4(f2bf(f.x), f2bf(f.y), f2bf(f.z), f2bf(f.w));
      }
    }
    __syncthreads();
    {
      int nw = t >> 4, k4 = (t & 15) * 4;
#pragma unroll
      for (int i = 0; i < 4; ++i) {
        int n = nw + 16 * i;
        ushort4 o = make_ushort4(ts[k4 + 0][n], ts[k4 + 1][n], ts[k4 + 2][n],
                                 ts[k4 + 3][n]);
        *(ushort4*)&valT[((b * 512) + n0 + n) * 512 + k0 + k4] = o;
      }
    }
  }
}

// ---------------------------------------------------------------------------
// K2: S[q,k] = sum_h v[h]/(A[q,h]*B[k,h]+1);  attn = softmax_k(-2S).
// 4 q-rows/block (each B dword + unpack feeds 8 cells). No LDS/barriers in
// hot loop. B from BexpT[h][k]: lane owns k-pair (2l,2l+1), in-loop coalesced
// dword loads (compiler schedules; reg-dbuf was a regression, r11). k-parity
// in packed-f32 halves. A,v SGPR-broadcast via 5x s_load_dwordx8 per 8-h
// chunk (single lgkmcnt(0): SMEM returns out of order).
// grid (128,8) = 4 blocks/CU, 4 waves/SIMD.
// ---------------------------------------------------------------------------
__global__ __launch_bounds__(256, 4) void k_score_softmax(
    const float* __restrict__ Aexp, const unsigned short* __restrict__ BexpT,
    const float* __restrict__ vw, float* __restrict__ attn) {
  __shared__ float red[4][4];

  const int tid = threadIdx.x;
  const int b = blockIdx.y;
  const int qbase = blockIdx.x * 4;
  const int wav = tid >> 6;   // k-quarter
  const int lane = tid & 63;

  const unsigned* const bbase32 = (const unsigned*)(BexpT + b * 512);
  const int kidx = wav * 64 + lane;  // dword index within a k-row

  const float* const pa0 =
      Aexp + __builtin_amdgcn_readfirstlane((b * 512 + qbase) * 128);
  const float* const pa1 = pa0 + 128;
  const float* const pa2 = pa0 + 256;
  const float* const pa3 = pa0 + 384;
  const float* const pv = vw;

  f32x2 acc0 = {0.f, 0.f}, acc1 = {0.f, 0.f};
  f32x2 acc2 = {0.f, 0.f}, acc3 = {0.f, 0.f};

#pragma unroll
  for (int ch = 0; ch < 16; ++ch) {  // 8 h per chunk
    f32x8s sa0, sa1, sa2, sa3, sv;
    unsigned soff = (unsigned)(ch * 32);
    asm volatile(
        "s_load_dwordx8 %0, %5, %10\n\t"
        "s_load_dwordx8 %1, %6, %10\n\t"
        "s_load_dwordx8 %2, %7, %10\n\t"
        "s_load_dwordx8 %3, %8, %10\n\t"
        "s_load_dwordx8 %4, %9, %10"
        : "=&s"(sa0), "=&s"(sa1), "=&s"(sa2), "=&s"(sa3), "=&s"(sv)
        : "s"(pa0), "s"(pa1), "s"(pa2), "s"(pa3), "s"(pv), "s"(soff));

    unsigned u[8];
#pragma unroll
    for (int j = 0; j < 8; ++j)
      u[j] = bbase32[ch * 16384 + j * 2048 + kidx];

    asm volatile("s_waitcnt lgkmcnt(0)"
                 : "+s"(sa0), "+s"(sa1), "+s"(sa2), "+s"(sa3), "+s"(sv));

#pragma unroll
    for (int g = 0; g < 2; ++g) {
      f32x2 b0 = unpack_bf2(u[g * 4 + 0]);
      f32x2 b1 = unpack_bf2(u[g * 4 + 1]);
      f32x2 b2 = unpack_bf2(u[g * 4 + 2]);
      f32x2 b3 = unpack_bf2(u[g * 4 + 3]);
      const int h = g * 4;
      cell4k(sa0[h], sa0[h + 1], sa0[h + 2], sa0[h + 3], b0, b1, b2, b3,
             sv[h], sv[h + 1], sv[h + 2], sv[h + 3], acc0);
      cell4k(sa1[h], sa1[h + 1], sa1[h + 2], sa1[h + 3], b0, b1, b2, b3,
             sv[h], sv[h + 1], sv[h + 2], sv[h + 3], acc1);
      cell4k(sa2[h], sa2[h + 1], sa2[h + 2], sa2[h + 3], b0, b1, b2, b3,
             sv[h], sv[h + 1], sv[h + 2], sv[h + 3], acc2);
      cell4k(sa3[h], sa3[h + 1], sa3[h + 2], sa3[h + 3], b0, b1, b2, b3,
             sv[h], sv[h + 1], sv[h + 2], sv[h + 3], acc3);
    }
  }

  // softmax over k of (-2S): max(score) <-> min(S). k spans lanes+waves.
  float mn0 = fminf(acc0.x, acc0.y);
  float mn1 = fminf(acc1.x, acc1.y);
  float mn2 = fminf(acc2.x, acc2.y);
  float mn3 = fminf(acc3.x, acc3.y);
#pragma unroll
  for (int off = 32; off > 0; off >>= 1) {
    mn0 = fminf(mn0, __shfl_xor(mn0, off));
    mn1 = fminf(mn1, __shfl_xor(mn1, off));
    mn2 = fminf(mn2, __shfl_xor(mn2, off));
    mn3 = fminf(mn3, __shfl_xor(mn3, off));
  }
  if (lane == 0) {
    red[wav][0] = mn0; red[wav][1] = mn1; red[wav][2] = mn2; red[wav][3] = mn3;
  }
  __syncthreads();
  mn0 = fminf(fminf(red[0][0], red[1][0]), fminf(red[2][0], red[3][0]));
  mn1 = fminf(fminf(red[0][1], red[1][1]), fminf(red[2][1], red[3][1]));
  mn2 = fminf(fminf(red[0][2], red[1][2]), fminf(red[2][2], red[3][2]));
  mn3 = fminf(fminf(red[0][3], red[1][3]), fminf(red[2][3], red[3][3]));
  __syncthreads();  // before red reuse

  float P0e = fexp2((mn0 - acc0.x) * TWO_LOG2E);
  float P0o = fexp2((mn0 - acc0.y) * TWO_LOG2E);
  float P1e = fexp2((mn1 - acc1.x) * TWO_LOG2E);
  float P1o = fexp2((mn1 - acc1.y) * TWO_LOG2E);
  float P2e = fexp2((mn2 - acc2.x) * TWO_LOG2E);
  float P2o = fexp2((mn2 - acc2.y) * TWO_LOG2E);
  float P3e = fexp2((mn3 - acc3.x) * TWO_LOG2E);
  float P3o = fexp2((mn3 - acc3.y) * TWO_LOG2E);
  float s0 = P0e + P0o, s1 = P1e + P1o, s2 = P2e + P2o, s3 = P3e + P3o;
#pragma unroll
  for (int off = 32; off > 0; off >>= 1) {
    s0 += __shfl_xor(s0, off);
    s1 += __shfl_xor(s1, off);
    s2 += __shfl_xor(s2, off);
    s3 += __shfl_xor(s3, off);
  }
  if (lane == 0) {
    red[wav][0] = s0; red[wav][1] = s1; red[wav][2] = s2; red[wav][3] = s3;
  }
  __syncthreads();
  float r0 = frcp(red[0][0] + red[1][0] + red[2][0] + red[3][0]);
  float r1 = frcp(red[0][1] + red[1][1] + red[2][1] + red[3][1]);
  float r2 = frcp(red[0][2] + red[1][2] + red[2][2] + red[3][2]);
  float r3 = frcp(red[0][3] + red[1][3] + red[2][3] + red[3][3]);

  const int row0 = (b * 512 + qbase) * 512;
  const int k0 = kidx * 2;
  *(float2*)&attn[row0 + k0] = make_float2(P0e * r0, P0o * r0);
  *(float2*)&attn[row0 + 512 + k0] = make_float2(P1e * r1, P1o * r1);
  *(float2*)&attn[row0 + 1024 + k0] = make_float2(P2e * r2, P2o * r2);
  *(float2*)&attn[row0 + 1536 + k0] = make_float2(P3e * r3, P3o * r3);
}

// ---------------------------------------------------------------------------
// K3: context[b] = attn[b] @ value[b] via bf16 MFMA 16x16x32.
// Tile 64x64, BK=64, 4 waves (2x2), wave tile 32x32 (2x2 frags).
// grid (8,8,8), block 256.
// ---------------------------------------------------------------------------
__global__ __launch_bounds__(256) void k_context_mfma(
    const float* __restrict__ attn, const unsigned short* __restrict__ valT,
    float* __restrict__ ctx) {
  __shared__ __align__(16) char At[64 * 128];  // [m][k] bf16 swizzled, 8KB
  __shared__ __align__(16) char Bt[64 * 128];  // [n][k] bf16 swizzled, 8KB

  const int t = threadIdx.x;
  const int b = blockIdx.z;
  const int m0 = blockIdx.y * 64, n0 = blockIdx.x * 64;
  const int w = t >> 6, l = t & 63;
  const int wr = w >> 1, wc = w & 1;

  f32x4v acc[2][2];
  acc[0][0] = 0; acc[0][1] = 0; acc[1][0] = 0; acc[1][1] = 0;

  const int sr = t >> 2;
  const int sg = (t & 3);
  const int sswz = sr & 7;

  for (int k0 = 0; k0 < 512; k0 += 64) {
    if (k0) __syncthreads();
    {  // stage A: 16 f32 -> 16 bf16 per thread
      const float* src = &attn[(b * 512 + m0 + sr) * 512 + k0 + sg * 16];
      char* dst = At + sr * 128;
#pragma unroll
      for (int h = 0; h < 2; ++h) {
        float4 f0 = *(const float4*)(src + h * 8);
        float4 f1 = *(const float4*)(src + h * 8 + 4);
        uint4 p = make_uint4(pack2bf(f0.x, f0.y), pack2bf(f0.z, f0.w),
                             pack2bf(f1.x, f1.y), pack2bf(f1.z, f1.w));
        int g = sg * 2 + h;
        *(uint4*)(dst + ((g ^ sswz) << 4)) = p;
      }
      // stage B^T: 32 bf16 per thread (already bf16)
      const unsigned short* srcb = &valT[(b * 512 + n0 + sr) * 512 + k0];
      char* dstb = Bt + sr * 128;
#pragma unroll
      for (int h = 0; h < 2; ++h) {
        int g = sg + h * 4;
        uint4 vb = *(const uint4*)(srcb + g * 8);
        *(uint4*)(dstb + ((g ^ sswz) << 4)) = vb;
      }
    }
    __syncthreads();
#pragma unroll
    for (int ks = 0; ks < 2; ++ks) {
      const int gb = ks * 4 + (l >> 4);
      short8 af[2], bf_[2];
#pragma unroll
      for (int mi = 0; mi < 2; ++mi) {
        int ra = wr * 32 + mi * 16 + (l & 15);
        af[mi] = *(const short8*)(At + ra * 128 + ((gb ^ (ra & 7)) << 4));
      }
#pragma unroll
      for (int ni = 0; ni < 2; ++ni) {
        int rb = wc * 32 + ni * 16 + (l & 15);
        bf_[ni] = *(const short8*)(Bt + rb * 128 + ((gb ^ (rb & 7)) << 4));
      }
#pragma unroll
      for (int mi = 0; mi < 2; ++mi)
#pragma unroll
        for (int ni = 0; ni < 2; ++ni)
          acc[mi][ni] = __builtin_amdgcn_mfma_f32_16x16x32_bf16(
              af[mi], bf_[ni], acc[mi][ni], 0, 0, 0);
    }
  }
  __syncthreads();
#pragma unroll
  for (int mi = 0; mi < 2; ++mi)
#pragma unroll
    for (int ni = 0; ni < 2; ++ni) {
      int col = n0 + wc * 32 + ni * 16 + (l & 15);
#pragma unroll
      for (int j = 0; j < 4; ++j) {
        int row = m0 + wr * 32 + mi * 16 + (l >> 4) * 4 + j;
        ctx[(b * 512 + row) * 512 + col] = acc[mi][ni][j];
      }
    }
}

extern "C" void kernel_launch(void* const* d_in, const int* in_sizes, int n_in,
                              void* d_out, int out_size, void* d_ws, size_t ws_size,
                              hipStream_t stream) {
  const float* query = (const float*)d_in[0];
  const float* key   = (const float*)d_in[1];
  const float* value = (const float*)d_in[2];
  const float* w1    = (const float*)d_in[3];
  const float* w2    = (const float*)d_in[4];
  const float* v     = (const float*)d_in[5];

  float* attn = (float*)d_out;
  float* ctx  = attn + 8 * 512 * 512;

  float* Aexp = (float*)d_ws;                                    // 4096*128 f32
  unsigned short* BexpT = (unsigned short*)(Aexp + 4096 * 128);  // 128*4096 bf16
  unsigned short* valT = BexpT + 128 * 4096;                     // 8*512*512 bf16

  k_pre<<<dim3(512, 2), 256, 0, stream>>>(query, key, w1, w2, value,
                                          Aexp, BexpT, valT);
  k_score_softmax<<<dim3(128, 8), 256, 0, stream>>>(Aexp, BexpT, v, attn);
  k_context_mfma<<<dim3(8, 8, 8), 256, 0, stream>>>(attn, valT, ctx);
}